// Round 5
// baseline (236.360 us; speedup 1.0000x reference)
//
#include <hip/hip_runtime.h>
#include <stdint.h>

#define M_DIM 8192
#define N_DIM 4096
#define K_DIM 4096

typedef float f32x4 __attribute__((ext_vector_type(4)));
typedef int   i32x4 __attribute__((ext_vector_type(4)));
typedef int   i32x8 __attribute__((ext_vector_type(8)));

// ---------------- fused amax (x and w) via uint-bits atomicMax ----------------
__global__ __launch_bounds__(256) void amax2_kernel(const float* __restrict__ x,
                                                    const float* __restrict__ wgt,
                                                    unsigned int* __restrict__ ws_u) {
    const int which = blockIdx.y;
    const float4* p = (const float4*)(which ? wgt : x);
    const int n4 = (which ? N_DIM : M_DIM) * (K_DIM / 4);
    int tid = blockIdx.x * blockDim.x + threadIdx.x;
    int stride = gridDim.x * blockDim.x;
    float m = 0.0f;
    for (int i = tid; i < n4; i += stride) {
        float4 v = p[i];
        m = fmaxf(m, fmaxf(fmaxf(fabsf(v.x), fabsf(v.y)),
                           fmaxf(fabsf(v.z), fabsf(v.w))));
    }
#pragma unroll
    for (int off = 32; off > 0; off >>= 1)
        m = fmaxf(m, __shfl_down(m, off, 64));
    __shared__ float sm[4];
    if ((threadIdx.x & 63) == 0) sm[threadIdx.x >> 6] = m;
    __syncthreads();
    if (threadIdx.x == 0) {
        m = fmaxf(fmaxf(sm[0], sm[1]), fmaxf(sm[2], sm[3]));
        atomicMax(ws_u + which, __float_as_uint(m));  // values >= 0: bit order == float order
    }
}

// ---------------- fused quantize f32 -> fp8 e4m3fn (packed 4/uint) -------------
__global__ __launch_bounds__(256) void quant2_kernel(const float* __restrict__ x,
                                                     const float* __restrict__ wgt,
                                                     unsigned int* __restrict__ xq,
                                                     unsigned int* __restrict__ wq,
                                                     const unsigned int* __restrict__ ws_u) {
    const int which = blockIdx.y;
    const float4* p = (const float4*)(which ? wgt : x);
    unsigned int* outp = which ? wq : xq;
    const int n4 = (which ? N_DIM : M_DIM) * (K_DIM / 4);
    float amax = fmaxf(__uint_as_float(ws_u[which]), 1e-12f);
    float scale = 448.0f / amax;
    int tid = blockIdx.x * blockDim.x + threadIdx.x;
    int stride = gridDim.x * blockDim.x;
    for (int i = tid; i < n4; i += stride) {
        float4 v = p[i];
        float a = fminf(fmaxf(v.x * scale, -448.0f), 448.0f);
        float b = fminf(fmaxf(v.y * scale, -448.0f), 448.0f);
        float c = fminf(fmaxf(v.z * scale, -448.0f), 448.0f);
        float d = fminf(fmaxf(v.w * scale, -448.0f), 448.0f);
        int w = __builtin_amdgcn_cvt_pk_fp8_f32(a, b, 0, false);
        w = __builtin_amdgcn_cvt_pk_fp8_f32(c, d, w, true);
        outp[i] = (unsigned int)w;
    }
}

// ---------------- MX-fp8 GEMM, 256x256 tile, full-tile read-ahead -------------
__device__ __forceinline__ void gld16(const void* g, void* l) {
    __builtin_amdgcn_global_load_lds(
        (const __attribute__((address_space(1))) void*)g,
        (__attribute__((address_space(3))) void*)l, 16, 0, 0);
}

#define MFMA_MX(a, b, c) __builtin_amdgcn_mfma_scale_f32_16x16x128_f8f6f4( \
    (a), (b), (c), 0, 0, 0, 0x7F7F7F7F, 0, 0x7F7F7F7F)

// LDS: A bufs [0,32K),[32K,64K); B bufs [64K,96K),[96K,128K).
// Tile [256 rows][128 B], 16B-chunk XOR swizzle (chunk ^= row&7); linear dest,
// pre-swizzled global source, XOR on read address (rule #21: both sides).
// K-loop (1 phase/tile): bar; stage 8 units of t+1 -> nbuf; vmcnt(8) counted
// (t+1's 8 loads remain in flight); bar; issue all 24 ds_read_b128; 32 MFMAs
// under compiler fine-grained lgkmcnt -> DS pipe streams under MFMA pipe.
__global__ __launch_bounds__(512, 2) void gemm_fp8_kernel(
    const uint8_t* __restrict__ Aq,   // [M][K] fp8
    const uint8_t* __restrict__ Bq,   // [N][K] fp8
    const float* __restrict__ bias,   // [N]
    const unsigned int* __restrict__ ws_u,
    float* __restrict__ out)          // [M][N] f32
{
    __shared__ uint8_t lds[131072];

    const int tid = threadIdx.x;
    const int w = tid >> 6, l = tid & 63;

    // XCD swizzle (512 blocks, %8==0): 32 M-tiles x 16 N-tiles
    const int cpx = (int)gridDim.x >> 3;
    const int bid = (int)blockIdx.x;
    const int swz = (bid & 7) * cpx + (bid >> 3);
    const int bm = swz >> 4, bn = swz & 15;

    const uint8_t* gA = Aq + (size_t)bm * 256 * K_DIM;
    const uint8_t* gB = Bq + (size_t)bn * 256 * K_DIM;

    // staging constants: thread t -> row idx (+64r), dest chunk p, src chunk p^(row&7)
    const int idx = tid >> 3, p = tid & 7;
    const int srcX = ((p ^ (idx & 7)) << 4);
    const uint8_t* aRow = gA + (size_t)idx * K_DIM + srcX;
    const uint8_t* bRow = gB + (size_t)idx * K_DIM + srcX;

    // fragment-read constants
    const int wr = w >> 2, wc = w & 3;       // 2M x 4N wave grid, 128x64 per wave
    const int lr = l & 15, g = l >> 4;
    const int oLo = (((2 * g) ^ (lr & 7)) << 4);
    const int oHi = (((2 * g + 1) ^ (lr & 7)) << 4);
    const int rowA0 = wr * 128 + lr;
    const int rowB0 = wc * 64 + lr;

    auto stageAll = [&](int bb, int t1) {
        const size_t k0 = (size_t)t1 * 128;
        uint8_t* la = &lds[bb * 32768 + tid * 16];
        uint8_t* lb = &lds[65536 + bb * 32768 + tid * 16];
#pragma unroll
        for (int r = 0; r < 4; ++r)
            gld16(aRow + (size_t)(r << 6) * K_DIM + k0, la + r * 8192);
#pragma unroll
        for (int r = 0; r < 4; ++r)
            gld16(bRow + (size_t)(r << 6) * K_DIM + k0, lb + r * 8192);
    };
    auto ldf = [&](const uint8_t* base, int row) -> i32x8 {
        const uint8_t* q = base + (row << 7);
        i32x4 lo = *(const i32x4*)(q + oLo);
        i32x4 hi = *(const i32x4*)(q + oHi);
        return __builtin_shufflevector(lo, hi, 0, 1, 2, 3, 4, 5, 6, 7);
    };

    f32x4 acc[8][4] = {};

    // prologue: stage tile 0 -> buf 0
    stageAll(0, 0);

#pragma unroll 2
    for (int t = 0; t < 32; ++t) {
        const int buf = t & 1;
        const uint8_t* lab = &lds[buf * 32768];
        const uint8_t* lbb = &lds[65536 + buf * 32768];

        __builtin_amdgcn_s_barrier();          // prev reads of nbuf all retired
        if (t < 31) {
            stageAll(buf ^ 1, t + 1);          // outstanding <= 16
            asm volatile("s_waitcnt vmcnt(8)" ::: "memory");  // tile t's 8 done
        } else {
            asm volatile("s_waitcnt vmcnt(0)" ::: "memory");
        }
        __builtin_amdgcn_s_barrier();          // tile t visible to all waves

        // issue all reads, first-needed first; compiler interleaves lgkmcnt
        i32x8 bv0 = ldf(lbb, rowB0);
        i32x8 bv1 = ldf(lbb, rowB0 + 16);
        i32x8 av0 = ldf(lab, rowA0);
        i32x8 av1 = ldf(lab, rowA0 + 16);
        i32x8 av2 = ldf(lab, rowA0 + 32);
        i32x8 av3 = ldf(lab, rowA0 + 48);
        i32x8 bv2 = ldf(lbb, rowB0 + 32);
        i32x8 bv3 = ldf(lbb, rowB0 + 48);
        i32x8 av4 = ldf(lab, rowA0 + 64);
        i32x8 av5 = ldf(lab, rowA0 + 80);
        i32x8 av6 = ldf(lab, rowA0 + 96);
        i32x8 av7 = ldf(lab, rowA0 + 112);

        __builtin_amdgcn_s_setprio(1);
        acc[0][0] = MFMA_MX(av0, bv0, acc[0][0]);
        acc[0][1] = MFMA_MX(av0, bv1, acc[0][1]);
        acc[1][0] = MFMA_MX(av1, bv0, acc[1][0]);
        acc[1][1] = MFMA_MX(av1, bv1, acc[1][1]);
        acc[2][0] = MFMA_MX(av2, bv0, acc[2][0]);
        acc[2][1] = MFMA_MX(av2, bv1, acc[2][1]);
        acc[3][0] = MFMA_MX(av3, bv0, acc[3][0]);
        acc[3][1] = MFMA_MX(av3, bv1, acc[3][1]);
        acc[0][2] = MFMA_MX(av0, bv2, acc[0][2]);
        acc[0][3] = MFMA_MX(av0, bv3, acc[0][3]);
        acc[1][2] = MFMA_MX(av1, bv2, acc[1][2]);
        acc[1][3] = MFMA_MX(av1, bv3, acc[1][3]);
        acc[2][2] = MFMA_MX(av2, bv2, acc[2][2]);
        acc[2][3] = MFMA_MX(av2, bv3, acc[2][3]);
        acc[3][2] = MFMA_MX(av3, bv2, acc[3][2]);
        acc[3][3] = MFMA_MX(av3, bv3, acc[3][3]);
        acc[4][0] = MFMA_MX(av4, bv0, acc[4][0]);
        acc[4][1] = MFMA_MX(av4, bv1, acc[4][1]);
        acc[5][0] = MFMA_MX(av5, bv0, acc[5][0]);
        acc[5][1] = MFMA_MX(av5, bv1, acc[5][1]);
        acc[6][0] = MFMA_MX(av6, bv0, acc[6][0]);
        acc[6][1] = MFMA_MX(av6, bv1, acc[6][1]);
        acc[7][0] = MFMA_MX(av7, bv0, acc[7][0]);
        acc[7][1] = MFMA_MX(av7, bv1, acc[7][1]);
        acc[4][2] = MFMA_MX(av4, bv2, acc[4][2]);
        acc[4][3] = MFMA_MX(av4, bv3, acc[4][3]);
        acc[5][2] = MFMA_MX(av5, bv2, acc[5][2]);
        acc[5][3] = MFMA_MX(av5, bv3, acc[5][3]);
        acc[6][2] = MFMA_MX(av6, bv2, acc[6][2]);
        acc[6][3] = MFMA_MX(av6, bv3, acc[6][3]);
        acc[7][2] = MFMA_MX(av7, bv2, acc[7][2]);
        acc[7][3] = MFMA_MX(av7, bv3, acc[7][3]);
        __builtin_amdgcn_s_setprio(0);
    }

    // ---- epilogue: scale by (amax_x/448)*(amax_w/448), add bias
    const float ax = fmaxf(__uint_as_float(ws_u[0]), 1e-12f);
    const float aw = fmaxf(__uint_as_float(ws_u[1]), 1e-12f);
    const float inv = (ax * (1.0f / 448.0f)) * (aw * (1.0f / 448.0f));

    const int orow0 = bm * 256 + wr * 128 + g * 4;   // D: row=(lane>>4)*4+reg
    const int ocol0 = bn * 256 + wc * 64 + lr;       // D: col=lane&15
#pragma unroll
    for (int mb = 0; mb < 8; ++mb) {
#pragma unroll
        for (int nb = 0; nb < 4; ++nb) {
            const int col = ocol0 + nb * 16;
            const float bvv = bias[col];
#pragma unroll
            for (int j = 0; j < 4; ++j) {
                const int row = orow0 + mb * 16 + j;
                out[(size_t)row * N_DIM + col] = acc[mb][nb][j] * inv + bvv;
            }
        }
    }
}

// ---------------- launch ----------------
extern "C" void kernel_launch(void* const* d_in, const int* in_sizes, int n_in,
                              void* d_out, int out_size, void* d_ws, size_t ws_size,
                              hipStream_t stream) {
    const float* x    = (const float*)d_in[0];   // [8192, 4096]
    const float* wgt  = (const float*)d_in[1];   // [4096, 4096]
    const float* bias = (const float*)d_in[2];   // [4096]
    float* out = (float*)d_out;                  // [8192, 4096] f32

    unsigned int* ws_u = (unsigned int*)d_ws;
    uint8_t* xq = (uint8_t*)d_ws + 256;
    uint8_t* wq = xq + (size_t)M_DIM * K_DIM;

    hipMemsetAsync(d_ws, 0, 8, stream);          // zero both amax slots

    dim3 ga(1024, 2);
    amax2_kernel<<<ga, 256, 0, stream>>>(x, wgt, ws_u);

    dim3 gq(2048, 2);
    quant2_kernel<<<gq, 256, 0, stream>>>(x, wgt, (unsigned int*)xq,
                                          (unsigned int*)wq, ws_u);

    gemm_fp8_kernel<<<(M_DIM / 256) * (N_DIM / 256), 512, 0, stream>>>(
        xq, wq, bias, ws_u, out);
}

// Round 6
// 221.450 us; speedup vs baseline: 1.0673x; 1.0673x over previous
//
#include <hip/hip_runtime.h>
#include <stdint.h>

#define M_DIM 8192
#define N_DIM 4096
#define K_DIM 4096

typedef float f32x4 __attribute__((ext_vector_type(4)));
typedef int   i32x4 __attribute__((ext_vector_type(4)));
typedef int   i32x8 __attribute__((ext_vector_type(8)));

// ---------------- fused amax (x and w) via uint-bits atomicMax ----------------
__global__ __launch_bounds__(256) void amax2_kernel(const float* __restrict__ x,
                                                    const float* __restrict__ wgt,
                                                    unsigned int* __restrict__ ws_u) {
    const int which = blockIdx.y;
    const float4* p = (const float4*)(which ? wgt : x);
    const int n4 = (which ? N_DIM : M_DIM) * (K_DIM / 4);
    int tid = blockIdx.x * blockDim.x + threadIdx.x;
    int stride = gridDim.x * blockDim.x;
    float m = 0.0f;
    for (int i = tid; i < n4; i += stride) {
        float4 v = p[i];
        m = fmaxf(m, fmaxf(fmaxf(fabsf(v.x), fabsf(v.y)),
                           fmaxf(fabsf(v.z), fabsf(v.w))));
    }
#pragma unroll
    for (int off = 32; off > 0; off >>= 1)
        m = fmaxf(m, __shfl_down(m, off, 64));
    __shared__ float sm[4];
    if ((threadIdx.x & 63) == 0) sm[threadIdx.x >> 6] = m;
    __syncthreads();
    if (threadIdx.x == 0) {
        m = fmaxf(fmaxf(sm[0], sm[1]), fmaxf(sm[2], sm[3]));
        atomicMax(ws_u + which, __float_as_uint(m));  // values >= 0: bit order == float order
    }
}

// ---------------- fused quantize f32 -> fp8 e4m3fn (packed 4/uint) -------------
__global__ __launch_bounds__(256) void quant2_kernel(const float* __restrict__ x,
                                                     const float* __restrict__ wgt,
                                                     unsigned int* __restrict__ xq,
                                                     unsigned int* __restrict__ wq,
                                                     const unsigned int* __restrict__ ws_u) {
    const int which = blockIdx.y;
    const float4* p = (const float4*)(which ? wgt : x);
    unsigned int* outp = which ? wq : xq;
    const int n4 = (which ? N_DIM : M_DIM) * (K_DIM / 4);
    float amax = fmaxf(__uint_as_float(ws_u[which]), 1e-12f);
    float scale = 448.0f / amax;
    int tid = blockIdx.x * blockDim.x + threadIdx.x;
    int stride = gridDim.x * blockDim.x;
    for (int i = tid; i < n4; i += stride) {
        float4 v = p[i];
        float a = fminf(fmaxf(v.x * scale, -448.0f), 448.0f);
        float b = fminf(fmaxf(v.y * scale, -448.0f), 448.0f);
        float c = fminf(fmaxf(v.z * scale, -448.0f), 448.0f);
        float d = fminf(fmaxf(v.w * scale, -448.0f), 448.0f);
        int w = __builtin_amdgcn_cvt_pk_fp8_f32(a, b, 0, false);
        w = __builtin_amdgcn_cvt_pk_fp8_f32(c, d, w, true);
        outp[i] = (unsigned int)w;
    }
}

// ---------------- MX-fp8 GEMM, 256x256 tile, m201-style 4-phase schedule -------
__device__ __forceinline__ void gld16(const void* g, void* l) {
    __builtin_amdgcn_global_load_lds(
        (const __attribute__((address_space(1))) void*)g,
        (__attribute__((address_space(3))) void*)l, 16, 0, 0);
}

#define MFMA_MX(a, b, c) __builtin_amdgcn_mfma_scale_f32_16x16x128_f8f6f4( \
    (a), (b), (c), 0, 0, 0, 0x7F7F7F7F, 0, 0x7F7F7F7F)
#define BAR()    __builtin_amdgcn_s_barrier()
#define LGKM0()  asm volatile("s_waitcnt lgkmcnt(0)" ::: "memory")
#define VMCNT(n) asm volatile("s_waitcnt vmcnt(" #n ")" ::: "memory")
#define PRIO1()  __builtin_amdgcn_s_setprio(1)
#define PRIO0()  __builtin_amdgcn_s_setprio(0)

// LDS: A bufs [0,32K),[32K,64K); B bufs [64K,96K),[96K,128K).
// Tile [256 rows][128 B], 16B-chunk XOR swizzle (chunk ^= row&7); linear dest,
// pre-swizzled global source, XOR on read address (rule #21: both sides).
// Per K-tile, 4 phases, each: {ds-reads; stage 1 unit(t+1); bar; lgkmcnt(0);
// setprio(1); 8 MFMA; setprio(0); [counted vmcnt]; bar}.  Stage order
// UA0,UB0,UA1,UB1; ledger: vmcnt(2)@P0-end retires UA1,UB1(t) (oldest 4 of 6);
// vmcnt(4)@P3-end retires UA0,UB0(t+1) (oldest 4 of 8). Never vmcnt(0) in-loop.
__global__ __launch_bounds__(512, 2) void gemm_fp8_kernel(
    const uint8_t* __restrict__ Aq,   // [M][K] fp8
    const uint8_t* __restrict__ Bq,   // [N][K] fp8
    const float* __restrict__ bias,   // [N]
    const unsigned int* __restrict__ ws_u,
    float* __restrict__ out)          // [M][N] f32
{
    __shared__ uint8_t lds[131072];

    const int tid = threadIdx.x;
    const int w = tid >> 6, l = tid & 63;

    // XCD swizzle (512 blocks, %8==0): 32 M-tiles x 16 N-tiles
    const int cpx = (int)gridDim.x >> 3;
    const int bid = (int)blockIdx.x;
    const int swz = (bid & 7) * cpx + (bid >> 3);
    const int bm = swz >> 4, bn = swz & 15;

    const uint8_t* gA = Aq + (size_t)bm * 256 * K_DIM;
    const uint8_t* gB = Bq + (size_t)bn * 256 * K_DIM;

    // staging: thread t -> dest chunk p of row idx(+unit offset); src chunk p^(row&7)
    const int idx = tid >> 3, p = tid & 7;
    const int srcX = ((p ^ (idx & 7)) << 4);
    const int rB = (idx & 31) + ((idx >> 5) << 6);
    const uint8_t* aRow = gA + (size_t)idx * K_DIM + srcX;
    const uint8_t* bRow = gB + (size_t)rB * K_DIM + srcX;
    const int dA = tid * 16;
    const int dB = tid * 16 + ((tid >> 8) << 12);

    // fragment-read constants
    const int wr = w >> 2, wc = w & 3;       // 2M x 4N wave grid, 128x64 per wave
    const int lr = l & 15, g = l >> 4;
    const int oLo = (((2 * g) ^ (lr & 7)) << 4);
    const int oHi = (((2 * g + 1) ^ (lr & 7)) << 4);
    const int rowA0 = wr * 128 + lr;
    const int rowB0 = wc * 64 + lr;

    auto stA = [&](int bb, int kn, int rbase) {
        gld16(aRow + (size_t)rbase * K_DIM + kn,
              &lds[bb * 32768 + rbase * 128 + dA]);
    };
    auto stB = [&](int bb, int kn, int boff, int r) {
        gld16(bRow + (size_t)(boff + (r << 7)) * K_DIM + kn,
              &lds[65536 + bb * 32768 + (boff << 7) + (r << 14) + dB]);
    };
    auto ldf = [&](const uint8_t* base, int row) -> i32x8 {
        const uint8_t* q = base + (row << 7);
        i32x4 lo = *(const i32x4*)(q + oLo);
        i32x4 hi = *(const i32x4*)(q + oHi);
        return __builtin_shufflevector(lo, hi, 0, 1, 2, 3, 4, 5, 6, 7);
    };

    f32x4 acc[8][4] = {};
    i32x8 av[4], bv[4];

    // prologue: stage tile 0 -> buf 0 (order UA0, UB0, UA1, UB1)
    stA(0, 0, 0);    stA(0, 0, 128);
    stB(0, 0, 0, 0); stB(0, 0, 0, 1);
    stA(0, 0, 64);   stA(0, 0, 192);
    stB(0, 0, 32, 0); stB(0, 0, 32, 1);
    VMCNT(4); BAR();                      // UA0,UB0(0) staged, visible to all

    for (int t = 0; t < 31; ++t) {
        const int buf = t & 1, nbuf = buf ^ 1;
        const int kn = (t + 1) * 128;
        const uint8_t* lab = &lds[buf * 32768];
        const uint8_t* lbb = &lds[65536 + buf * 32768];

        // ---- P0: reads av0-3,bv0-1; stage UA0(t+1)
        av[0] = ldf(lab, rowA0);      av[1] = ldf(lab, rowA0 + 16);
        av[2] = ldf(lab, rowA0 + 32); av[3] = ldf(lab, rowA0 + 48);
        bv[0] = ldf(lbb, rowB0);      bv[1] = ldf(lbb, rowB0 + 16);
        stA(nbuf, kn, 0); stA(nbuf, kn, 128);
        BAR(); LGKM0();
        PRIO1();
        acc[0][0] = MFMA_MX(av[0], bv[0], acc[0][0]);
        acc[0][1] = MFMA_MX(av[0], bv[1], acc[0][1]);
        acc[1][0] = MFMA_MX(av[1], bv[0], acc[1][0]);
        acc[1][1] = MFMA_MX(av[1], bv[1], acc[1][1]);
        acc[2][0] = MFMA_MX(av[2], bv[0], acc[2][0]);
        acc[2][1] = MFMA_MX(av[2], bv[1], acc[2][1]);
        acc[3][0] = MFMA_MX(av[3], bv[0], acc[3][0]);
        acc[3][1] = MFMA_MX(av[3], bv[1], acc[3][1]);
        PRIO0();
        VMCNT(2);                          // UA1,UB1(t) retired (oldest 4 of 6)
        BAR();

        // ---- P1: reads bv2-3; stage UB0(t+1)
        bv[2] = ldf(lbb, rowB0 + 32); bv[3] = ldf(lbb, rowB0 + 48);
        stB(nbuf, kn, 0, 0); stB(nbuf, kn, 0, 1);
        BAR(); LGKM0();
        PRIO1();
        acc[0][2] = MFMA_MX(av[0], bv[2], acc[0][2]);
        acc[0][3] = MFMA_MX(av[0], bv[3], acc[0][3]);
        acc[1][2] = MFMA_MX(av[1], bv[2], acc[1][2]);
        acc[1][3] = MFMA_MX(av[1], bv[3], acc[1][3]);
        acc[2][2] = MFMA_MX(av[2], bv[2], acc[2][2]);
        acc[2][3] = MFMA_MX(av[2], bv[3], acc[2][3]);
        acc[3][2] = MFMA_MX(av[3], bv[2], acc[3][2]);
        acc[3][3] = MFMA_MX(av[3], bv[3], acc[3][3]);
        PRIO0();
        BAR();

        // ---- P2: reads av4-7 (reuse av regs); stage UA1(t+1)
        av[0] = ldf(lab, rowA0 + 64); av[1] = ldf(lab, rowA0 + 80);
        av[2] = ldf(lab, rowA0 + 96); av[3] = ldf(lab, rowA0 + 112);
        stA(nbuf, kn, 64); stA(nbuf, kn, 192);
        BAR(); LGKM0();
        PRIO1();
        acc[4][0] = MFMA_MX(av[0], bv[0], acc[4][0]);
        acc[4][1] = MFMA_MX(av[0], bv[1], acc[4][1]);
        acc[5][0] = MFMA_MX(av[1], bv[0], acc[5][0]);
        acc[5][1] = MFMA_MX(av[1], bv[1], acc[5][1]);
        acc[6][0] = MFMA_MX(av[2], bv[0], acc[6][0]);
        acc[6][1] = MFMA_MX(av[2], bv[1], acc[6][1]);
        acc[7][0] = MFMA_MX(av[3], bv[0], acc[7][0]);
        acc[7][1] = MFMA_MX(av[3], bv[1], acc[7][1]);
        PRIO0();
        BAR();

        // ---- P3: no reads; stage UB1(t+1)
        stB(nbuf, kn, 32, 0); stB(nbuf, kn, 32, 1);
        BAR();
        PRIO1();
        acc[4][2] = MFMA_MX(av[0], bv[2], acc[4][2]);
        acc[4][3] = MFMA_MX(av[0], bv[3], acc[4][3]);
        acc[5][2] = MFMA_MX(av[1], bv[2], acc[5][2]);
        acc[5][3] = MFMA_MX(av[1], bv[3], acc[5][3]);
        acc[6][2] = MFMA_MX(av[2], bv[2], acc[6][2]);
        acc[6][3] = MFMA_MX(av[2], bv[3], acc[6][3]);
        acc[7][2] = MFMA_MX(av[3], bv[3 - 1], acc[7][2]);
        acc[7][3] = MFMA_MX(av[3], bv[3], acc[7][3]);
        PRIO0();
        VMCNT(4);                          // UA0,UB0(t+1) retired (oldest 4 of 8)
        BAR();
    }

    // ---- peeled last tile (t=31, buf=1): no staging
    {
        const uint8_t* lab = &lds[32768];
        const uint8_t* lbb = &lds[65536 + 32768];

        av[0] = ldf(lab, rowA0);      av[1] = ldf(lab, rowA0 + 16);
        av[2] = ldf(lab, rowA0 + 32); av[3] = ldf(lab, rowA0 + 48);
        bv[0] = ldf(lbb, rowB0);      bv[1] = ldf(lbb, rowB0 + 16);
#pragma unroll
        for (int m = 0; m < 4; ++m) {
            acc[m][0] = MFMA_MX(av[m], bv[0], acc[m][0]);
            acc[m][1] = MFMA_MX(av[m], bv[1], acc[m][1]);
        }
        VMCNT(0); BAR();                   // UA1,UB1(31) staged & visible
        bv[2] = ldf(lbb, rowB0 + 32); bv[3] = ldf(lbb, rowB0 + 48);
#pragma unroll
        for (int m = 0; m < 4; ++m) {
            acc[m][2] = MFMA_MX(av[m], bv[2], acc[m][2]);
            acc[m][3] = MFMA_MX(av[m], bv[3], acc[m][3]);
        }
        av[0] = ldf(lab, rowA0 + 64); av[1] = ldf(lab, rowA0 + 80);
        av[2] = ldf(lab, rowA0 + 96); av[3] = ldf(lab, rowA0 + 112);
#pragma unroll
        for (int m = 0; m < 4; ++m) {
            acc[4 + m][0] = MFMA_MX(av[m], bv[0], acc[4 + m][0]);
            acc[4 + m][1] = MFMA_MX(av[m], bv[1], acc[4 + m][1]);
            acc[4 + m][2] = MFMA_MX(av[m], bv[2], acc[4 + m][2]);
            acc[4 + m][3] = MFMA_MX(av[m], bv[3], acc[4 + m][3]);
        }
    }

    // ---- epilogue: scale by (amax_x/448)*(amax_w/448), add bias
    const float ax = fmaxf(__uint_as_float(ws_u[0]), 1e-12f);
    const float aw = fmaxf(__uint_as_float(ws_u[1]), 1e-12f);
    const float inv = (ax * (1.0f / 448.0f)) * (aw * (1.0f / 448.0f));

    const int orow0 = bm * 256 + wr * 128 + g * 4;   // D: row=(lane>>4)*4+reg
    const int ocol0 = bn * 256 + wc * 64 + lr;       // D: col=lane&15
#pragma unroll
    for (int mb = 0; mb < 8; ++mb) {
#pragma unroll
        for (int nb = 0; nb < 4; ++nb) {
            const int col = ocol0 + nb * 16;
            const float bvv = bias[col];
#pragma unroll
            for (int j = 0; j < 4; ++j) {
                const int row = orow0 + mb * 16 + j;
                out[(size_t)row * N_DIM + col] = acc[mb][nb][j] * inv + bvv;
            }
        }
    }
}

// ---------------- launch ----------------
extern "C" void kernel_launch(void* const* d_in, const int* in_sizes, int n_in,
                              void* d_out, int out_size, void* d_ws, size_t ws_size,
                              hipStream_t stream) {
    const float* x    = (const float*)d_in[0];   // [8192, 4096]
    const float* wgt  = (const float*)d_in[1];   // [4096, 4096]
    const float* bias = (const float*)d_in[2];   // [4096]
    float* out = (float*)d_out;                  // [8192, 4096] f32

    unsigned int* ws_u = (unsigned int*)d_ws;
    uint8_t* xq = (uint8_t*)d_ws + 256;
    uint8_t* wq = xq + (size_t)M_DIM * K_DIM;

    hipMemsetAsync(d_ws, 0, 8, stream);          // zero both amax slots

    dim3 ga(1024, 2);
    amax2_kernel<<<ga, 256, 0, stream>>>(x, wgt, ws_u);

    dim3 gq(2048, 2);
    quant2_kernel<<<gq, 256, 0, stream>>>(x, wgt, (unsigned int*)xq,
                                          (unsigned int*)wq, ws_u);

    gemm_fp8_kernel<<<(M_DIM / 256) * (N_DIM / 256), 512, 0, stream>>>(
        xq, wq, bias, ws_u, out);
}